// Round 6
// baseline (322.961 us; speedup 1.0000x reference)
//
#include <hip/hip_runtime.h>
#include <hip/hip_bf16.h>

#define D_ 1024
#define B_ 4
#define S_ 4096

typedef __attribute__((ext_vector_type(8))) short bf16x8;
typedef __attribute__((ext_vector_type(4))) float f32x4;
typedef __attribute__((ext_vector_type(4))) unsigned int u32x4;
typedef __attribute__((ext_vector_type(4))) unsigned short u16x4;

__device__ __forceinline__ unsigned short f2bf(float f) {
    unsigned int u = __builtin_bit_cast(unsigned int, f);
    u = u + 0x7fffu + ((u >> 16) & 1u);
    return (unsigned short)(u >> 16);
}
__device__ __forceinline__ unsigned int pk2(float a, float b) {
    return (unsigned int)f2bf(a) | ((unsigned int)f2bf(b) << 16);
}
__device__ __forceinline__ float bf2f(unsigned short h) {
    unsigned int u = ((unsigned int)h) << 16;
    return __builtin_bit_cast(float, u);
}
__device__ __forceinline__ void gload16(const void* g, void* l) {
    __builtin_amdgcn_global_load_lds(
        (const __attribute__((address_space(1))) void*)g,
        (__attribute__((address_space(3))) void*)l, 16, 0, 0);
}

// ---------------- elementwise helpers ----------------
__global__ __launch_bounds__(256)
void conv_bf16(const float* __restrict__ src, unsigned short* __restrict__ dst, int n8) {
    int i = blockIdx.x * blockDim.x + threadIdx.x;
    const int stride = gridDim.x * blockDim.x;
    for (; i < n8; i += stride) {
        f32x4 v0 = *(const f32x4*)(src + (size_t)i * 8);
        f32x4 v1 = *(const f32x4*)(src + (size_t)i * 8 + 4);
        u32x4 o;
        o[0] = pk2(v0[0], v0[1]);
        o[1] = pk2(v0[2], v0[3]);
        o[2] = pk2(v1[0], v1[1]);
        o[3] = pk2(v1[2], v1[3]);
        *(u32x4*)(dst + (size_t)i * 8) = o;
    }
}

__global__ __launch_bounds__(256)
void conv_bf16_w2(const float* __restrict__ s0, const float* __restrict__ s1,
                  unsigned short* __restrict__ d0, unsigned short* __restrict__ d1,
                  int n8_per) {
    int i = blockIdx.x * blockDim.x + threadIdx.x;
    const int stride = gridDim.x * blockDim.x;
    for (; i < 2 * n8_per; i += stride) {
        int w = i / n8_per;
        size_t j = (size_t)(i - w * n8_per) * 8;
        const float* s = w ? s1 : s0;
        unsigned short* d = w ? d1 : d0;
        f32x4 v0 = *(const f32x4*)(s + j);
        f32x4 v1 = *(const f32x4*)(s + j + 4);
        u32x4 o;
        o[0] = pk2(v0[0], v0[1]);
        o[1] = pk2(v0[2], v0[3]);
        o[2] = pk2(v1[0], v1[1]);
        o[3] = pk2(v1[2], v1[3]);
        *(u32x4*)(d + j) = o;
    }
}

// In-place segment reduce: E[b][i] = sum_seg P[b*split+seg][i], with E[b] stored
// AT P[b*split] (so every write address is read only by the SAME thread).
__global__ __launch_bounds__(256)
void reduceN_bf16_inplace(unsigned short* __restrict__ P, int split, int n8_total) {
    int t = blockIdx.x * blockDim.x + threadIdx.x;
    const int stride = gridDim.x * blockDim.x;
    const int DD = D_ * D_;
    for (; t < n8_total; t += stride) {
        size_t idx = (size_t)t * 8;
        int b = (int)(idx / DD);
        size_t i = idx % DD;
        float s[8];
#pragma unroll
        for (int k = 0; k < 8; ++k) s[k] = 0.f;
        for (int seg = 0; seg < split; ++seg) {
            const unsigned short* p = P + (size_t)(b * split + seg) * DD + i;
            u16x4 v0 = *(const u16x4*)p;
            u16x4 v1 = *(const u16x4*)(p + 4);
#pragma unroll
            for (int k = 0; k < 4; ++k) { s[k] += bf2f(v0[k]); s[4 + k] += bf2f(v1[k]); }
        }
        u16x4 o0, o1;
#pragma unroll
        for (int k = 0; k < 4; ++k) { o0[k] = f2bf(s[k]); o1[k] = f2bf(s[4 + k]); }
        unsigned short* e = P + (size_t)(b * split) * DD + i;
        *(u16x4*)e = o0;
        *(u16x4*)(e + 4) = o1;
    }
}

// ---------------- 128x128 2-phase kernel (proven; small F-GEMM only) ----------------
#define BM 128
#define BN 128
#define BK 64
#define NTHR 256

template<bool OUT_F32, bool TRANS, bool RELU>
__global__ __launch_bounds__(NTHR)
void gemm_nt(const unsigned short* __restrict__ Ap, const unsigned short* __restrict__ Bp,
             void* __restrict__ Op, int M, int N, int K, int klen, int split,
             long long sA, long long sB, long long sO)
{
    __shared__ char lds_a[BM * BK * 2];
    __shared__ char lds_b[BN * BK * 2];

    const int tid   = threadIdx.x;
    const int bz    = blockIdx.z;
    const int batch = bz / split;
    const int k0    = (bz % split) * klen;
    const int bm    = blockIdx.y * BM;
    const int bn    = blockIdx.x * BN;

    const unsigned short* Abase = Ap + (size_t)batch * sA + (size_t)bm * K;
    const unsigned short* Bbase = Bp + (size_t)batch * sB + (size_t)bn * K;

    const int lane = tid & 63;
    const int wave = tid >> 6;
    const int wm   = (wave >> 1) * 64;
    const int wn   = (wave & 1) * 64;
    const int l16  = lane & 15;
    const int lhi  = lane >> 4;

    const int srow0 = wave * 32 + (lane >> 3);
    const int schnk = (lane & 7) ^ (lane >> 3);
    const char* gA0 = (const char*)(Abase + (size_t)srow0 * K) + schnk * 16;
    const char* gB0 = (const char*)(Bbase + (size_t)srow0 * K) + schnk * 16;
    char* lA0 = lds_a + wave * 4096;
    char* lB0 = lds_b + wave * 4096;

    f32x4 acc[4][4];
#pragma unroll
    for (int i = 0; i < 4; ++i)
#pragma unroll
        for (int j = 0; j < 4; ++j)
            acc[i][j] = (f32x4){0.f, 0.f, 0.f, 0.f};

    for (int kt = k0; kt < k0 + klen; kt += BK) {
#pragma unroll
        for (int p = 0; p < 4; ++p)
            gload16(gA0 + ((size_t)p * 8 * K + kt) * 2, lA0 + p * 1024);
#pragma unroll
        for (int p = 0; p < 4; ++p)
            gload16(gB0 + ((size_t)p * 8 * K + kt) * 2, lB0 + p * 1024);
        __syncthreads();
#pragma unroll
        for (int kk = 0; kk < BK / 32; ++kk) {
            bf16x8 af[4], bfr[4];
#pragma unroll
            for (int i = 0; i < 4; ++i) {
                int row = wm + i * 16 + l16;
                int byt = (row * 128 + kk * 64 + lhi * 16) ^ ((row & 7) << 4);
                af[i] = *(const bf16x8*)(lds_a + byt);
            }
#pragma unroll
            for (int j = 0; j < 4; ++j) {
                int row = wn + j * 16 + l16;
                int byt = (row * 128 + kk * 64 + lhi * 16) ^ ((row & 7) << 4);
                bfr[j] = *(const bf16x8*)(lds_b + byt);
            }
#pragma unroll
            for (int i = 0; i < 4; ++i)
#pragma unroll
                for (int j = 0; j < 4; ++j)
                    acc[i][j] = __builtin_amdgcn_mfma_f32_16x16x32_bf16(af[i], bfr[j], acc[i][j], 0, 0, 0);
        }
        __syncthreads();
    }

    const size_t obase = (size_t)bz * (size_t)sO;
    if constexpr (!TRANS) {
#pragma unroll
        for (int i = 0; i < 4; ++i) {
            const int m0 = bm + wm + i * 16 + lhi * 4;
#pragma unroll
            for (int j = 0; j < 4; ++j) {
                const int n = bn + wn + j * 16 + l16;
#pragma unroll
                for (int r = 0; r < 4; ++r) {
                    float v = acc[i][j][r];
                    if constexpr (RELU) v = fmaxf(v, 0.f);
                    size_t addr = obase + (size_t)(m0 + r) * N + n;
                    if constexpr (OUT_F32) ((float*)Op)[addr] = v;
                    else ((unsigned short*)Op)[addr] = f2bf(v);
                }
            }
        }
    } else {
#pragma unroll
        for (int i = 0; i < 4; ++i) {
            const int m0 = bm + wm + i * 16 + lhi * 4;
#pragma unroll
            for (int j = 0; j < 4; ++j) {
                const int n = bn + wn + j * 16 + l16;
                u16x4 h;
#pragma unroll
                for (int r = 0; r < 4; ++r) {
                    float v = acc[i][j][r];
                    if constexpr (RELU) v = fmaxf(v, 0.f);
                    h[r] = f2bf(v);
                }
                *(u16x4*)((unsigned short*)Op + obase + (size_t)n * M + m0) = h;
            }
        }
    }
}

// ---------------- 256x256 register-pipelined kernel (round 6) ----------------
// Per K-tile: issue ALL 24 fragment ds_reads, then 64 MFMAs; the COMPILER's
// fine-grained lgkmcnt scheduling interleaves them (guide: m97 asm evidence),
// overlapping the LDS pipe with the MFMA pipe within each wave. Only 2
// s_barriers per K-tile. Region-free invariants (proven r4/r5 skeleton):
//   - LGKM0 after the MFMA block, before the barrier, certifies this wave's
//     reads retired; barrier certifies all waves -> safe to restage the buf.
//   - vmcnt(8) after each stage drains the OTHER buf's 8 loads (issued one
//     full compute-block earlier) while keeping the new 8 in flight.
#define CTILE 65536
#define CBOFF 32768

template<bool OUT_F32, bool TRANS, bool RELU>
__global__ __launch_bounds__(512, 2)
void gemm256(const unsigned short* __restrict__ Ap, const unsigned short* __restrict__ Bp,
             void* __restrict__ Op, int M, int N, int K, int klen, int split,
             long long sA, long long sB, long long sO)
{
    __shared__ char lds[131072];
    const int tid  = threadIdx.x;
    const int wave = tid >> 6;
    const int lane = tid & 63;

    // XCD-aware bijective block swizzle (all grids have nwg % 8 == 0)
    const int gx = gridDim.x, gy = gridDim.y;
    const int f   = blockIdx.x + gx * (blockIdx.y + gy * blockIdx.z);
    const int nwg = gx * gy * (int)gridDim.z;
    const int s   = (f & 7) * (nwg >> 3) + (f >> 3);
    const int lx  = s % gx;
    const int lyz = s / gx;
    const int ly  = lyz % gy;
    const int lz  = lyz / gy;

    const int batch = lz / split;
    const int k0    = (lz % split) * klen;
    const int bm    = ly * 256;
    const int bn    = lx * 256;

    const int wm  = (wave >> 2) * 128;
    const int wn  = (wave & 3) * 64;
    const int l16 = lane & 15, lhi = lane >> 4;

    const unsigned short* Abase = Ap + (size_t)batch * sA + (size_t)bm * K;
    const unsigned short* Bbase = Bp + (size_t)batch * sB + (size_t)bn * K;
    const int srow  = lane >> 3;
    const int schnk = (lane & 7) ^ srow;
    const size_t K2 = (size_t)K * 2;
    const char* gA = (const char*)Abase + (size_t)srow * K2 + (size_t)schnk * 16 + (size_t)k0 * 2;
    const char* gB = (const char*)Bbase + (size_t)srow * K2 + (size_t)schnk * 16 + (size_t)k0 * 2;

    f32x4 acc[8][4];
#pragma unroll
    for (int i = 0; i < 8; ++i)
#pragma unroll
        for (int j = 0; j < 4; ++j)
            acc[i][j] = (f32x4){0.f, 0.f, 0.f, 0.f};

    bf16x8 af[8][2], bfr[4][2];

    auto stageAB = [&](int c, int t) {   // 8 gload_lds: full A+B K-tile t -> buf c
#pragma unroll
        for (int h = 0; h < 2; ++h)
#pragma unroll
            for (int p = 0; p < 2; ++p) {
                gload16(gA + (size_t)t * 128 + (size_t)(h * 128 + wave * 16 + p * 8) * K2,
                        lds + c * CTILE + h * 16384 + wave * 2048 + p * 1024);
                gload16(gB + (size_t)t * 128 + (size_t)(h * 128 + wave * 16 + p * 8) * K2,
                        lds + c * CTILE + CBOFF + h * 16384 + wave * 2048 + p * 1024);
            }
    };
    auto ldall = [&](int c) {            // B first, then A: first MFMA ready after ~10 reads
#pragma unroll
        for (int j2 = 0; j2 < 4; ++j2)
#pragma unroll
            for (int kk = 0; kk < 2; ++kk) {
                int row = wn + j2 * 16 + l16;
                int byt = (row * 128 + kk * 64 + lhi * 16) ^ ((row & 7) << 4);
                bfr[j2][kk] = *(const bf16x8*)(lds + c * CTILE + CBOFF + byt);
            }
#pragma unroll
        for (int i4 = 0; i4 < 8; ++i4)
#pragma unroll
            for (int kk = 0; kk < 2; ++kk) {
                int row = wm + i4 * 16 + l16;
                int byt = (row * 128 + kk * 64 + lhi * 16) ^ ((row & 7) << 4);
                af[i4][kk] = *(const bf16x8*)(lds + c * CTILE + byt);
            }
    };
    auto mmall = [&]() {
        __builtin_amdgcn_s_setprio(1);
#pragma unroll
        for (int i4 = 0; i4 < 8; ++i4)
#pragma unroll
            for (int j2 = 0; j2 < 4; ++j2)
#pragma unroll
                for (int kk = 0; kk < 2; ++kk)
                    acc[i4][j2] = __builtin_amdgcn_mfma_f32_16x16x32_bf16(
                        af[i4][kk], bfr[j2][kk], acc[i4][j2], 0, 0, 0);
        __builtin_amdgcn_s_setprio(0);
    };

#define BAR()   __builtin_amdgcn_s_barrier()
#define LGKM0() asm volatile("s_waitcnt lgkmcnt(0)" ::: "memory")
#define VM8()   asm volatile("s_waitcnt vmcnt(8)" ::: "memory")

    const int NT = klen / 64;
    stageAB(0, 0); stageAB(1, 1);
    VM8();                 // drain buf0's 8, keep buf1's 8 in flight
    BAR();

    for (int itr = 0; itr < NT / 2; ++itr) {
        ldall(0); mmall();                 // compiler interleaves reads & MFMAs
        LGKM0(); BAR();                    // all waves done reading buf0
        stageAB(0, (2 * itr + 2) % NT);    // restage buf0 (latency hides under buf1 compute)
        VM8(); BAR();                      // buf1's stage certified resident
        ldall(1); mmall();
        LGKM0(); BAR();
        stageAB(1, (2 * itr + 3) % NT);
        VM8(); BAR();
    }
    asm volatile("s_waitcnt vmcnt(0)" ::: "memory");

    const size_t obase = (size_t)lz * (size_t)sO;
    if constexpr (!TRANS) {
#pragma unroll
        for (int i = 0; i < 8; ++i) {
            const int m0 = bm + wm + i * 16 + lhi * 4;
#pragma unroll
            for (int j = 0; j < 4; ++j) {
                const int n = bn + wn + j * 16 + l16;
#pragma unroll
                for (int r = 0; r < 4; ++r) {
                    float v = acc[i][j][r];
                    if constexpr (RELU) v = fmaxf(v, 0.f);
                    size_t addr = obase + (size_t)(m0 + r) * N + n;
                    if constexpr (OUT_F32) ((float*)Op)[addr] = v;
                    else ((unsigned short*)Op)[addr] = f2bf(v);
                }
            }
        }
    } else {
#pragma unroll
        for (int i = 0; i < 8; ++i) {
            const int m0 = bm + wm + i * 16 + lhi * 4;
#pragma unroll
            for (int j = 0; j < 4; ++j) {
                const int n = bn + wn + j * 16 + l16;
                u16x4 h;
#pragma unroll
                for (int r = 0; r < 4; ++r) {
                    float v = acc[i][j][r];
                    if constexpr (RELU) v = fmaxf(v, 0.f);
                    h[r] = f2bf(v);
                }
                *(u16x4*)((unsigned short*)Op + obase + (size_t)n * M + m0) = h;
            }
        }
    }
#undef BAR
#undef LGKM0
#undef VM8
}

extern "C" void kernel_launch(void* const* d_in, const int* in_sizes, int n_in,
                              void* d_out, int out_size, void* d_ws, size_t ws_size,
                              hipStream_t stream) {
    (void)in_sizes; (void)n_in; (void)out_size; (void)ws_size;
    const float* x  = (const float*)d_in[0];
    const float* Wa = (const float*)d_in[1];
    const float* Wb = (const float*)d_in[2];
    const float* Wc = (const float*)d_in[3];
    const float* Wd = (const float*)d_in[4];

    const long long SD  = (long long)S_ * D_;   // [S,D] elems
    const long long DD2 = (long long)D_ * D_;
    const size_t MB = 1024 * 1024;

    // ws (64MB): fused BC output [b][2048][S] bf16 = exactly 64MB.
    //   After E: dead -> A (non-trans) @0-32MB, Ft @32-40MB.
    unsigned short* BC  = (unsigned short*)d_ws;
    unsigned short* Ao  = (unsigned short*)d_ws;                        // reuses BC
    unsigned short* Ft  = (unsigned short*)((char*)d_ws + 32 * MB);     // reuses BC
    // d_out scratch (64MB): xb@0-32 | P(16 segs, 32MB)@32-64.
    //   Wbb@56,Wcb@58 (dead after projBC, overwritten by P segs 12-15).
    //   After reduce: Enorm[b] in-place at P[4b] (stride 4*DD2); P segs 1-2
    //   free -> Wdb@34, Wab@36 (converted late).
    char* ob = (char*)d_out;
    unsigned short* xb    = (unsigned short*)ob;
    unsigned short* Pp    = (unsigned short*)(ob + 32 * MB);
    unsigned short* Enorm = Pp;                 // batch stride 4*DD2
    unsigned short* Wdb   = (unsigned short*)(ob + 34 * MB);
    unsigned short* Wab   = (unsigned short*)(ob + 36 * MB);
    unsigned short* Wbb   = (unsigned short*)(ob + 56 * MB);   // Wbb|Wcb contiguous [2048][1024]
    unsigned short* Wcb   = (unsigned short*)(ob + 58 * MB);

    dim3 blk256(256, 1, 1);
    dim3 blk512(512, 1, 1);
    dim3 gBC(2048 / 256, S_ / 256, B_);        // (8,16,4) = 512
    dim3 gE(D_ / 256, D_ / 256, B_ * 4);       // (4,4,16) = 256, split-K=4
    dim3 gS(D_ / 256, S_ / 256, B_);           // (4,16,4) = 256
    dim3 gF(D_ / BN, D_ / BM, B_);             // (8,8,4)

    // 0) convert x and Wb|Wc
    conv_bf16<<<2048, blk256, 0, stream>>>(x, xb, (B_ * S_ * D_) / 8);
    conv_bf16_w2<<<512, blk256, 0, stream>>>(Wb, Wc, Wbb, Wcb, (D_ * D_) / 8);
    // 1) fused projections: BC[b][n][s] = relu(xb [Wb;Wc]^T)^T, n in [0,2048)
    gemm256<false, true,  true ><<<gBC, blk512, 0, stream>>>(xb, Wbb, BC, S_, 2048, D_, D_, 1, SD, 0, 2 * SD);
    // 2) E partials: P[b*4+seg][e][e'] = sum_{s in seg} Bm[s,e] C[s,e']
    //    A = BC (Bmt rows 0-1023), B = BC+SD (Ct rows), batch stride 2*SD
    gemm256<false, false, false><<<gE, blk512, 0, stream>>>(BC, BC + SD, Pp, D_, D_, S_, S_ / 4, 4, 2 * SD, 2 * SD, DD2);
    // 2b) Enorm[b] = sum_seg P  (in-place at P[4b])
    reduceN_bf16_inplace<<<2048, blk256, 0, stream>>>(Pp, 4, (B_ * D_ * D_) / 8);
    // 2c) convert Wd, Wa (into dead P segs 1-2)
    conv_bf16_w2<<<512, blk256, 0, stream>>>(Wd, Wa, Wdb, Wab, (D_ * D_) / 8);
    // 3) Ft[b][dout][e] = (Enorm[b] @ Wd^T)^T   (Enorm batch stride 4*DD2)
    gemm_nt<false, true,  false><<<gF, blk256, 0, stream>>>(Enorm, Wdb, Ft, D_, D_, D_, D_, 1, 4 * DD2, 0, DD2);
    // 4) A[b][s][e] = relu(xb Wa^T) -> ws@0 (BC dead)
    gemm256<false, false, true ><<<gS, blk512, 0, stream>>>(xb, Wab, Ao, S_, D_, D_, D_, 1, SD, 0, SD);
    // 5) out = relu(A @ Ft-rows) f32 -> d_out (reads only ws; overwrites d_out)
    gemm256<true,  false, true ><<<gS, blk512, 0, stream>>>(Ao, Ft, (float*)d_out, S_, D_, D_, D_, 1, SD, DD2, SD);
}